// Round 1
// baseline (460.773 us; speedup 1.0000x reference)
//
#include <hip/hip_runtime.h>
#include <cmath>

#define CTXL 50
#define NC 300    // NCOND
#define NH 256    // NHID
#define NT 256    // threads per block

// One block per batch element. 4 waves; wave w owns l-rows [13w, 13w+13)
// (rows 50,51 are zero pad, excluded from the mean); each lane owns 4
// hidden columns n0..n0+3. Inner loop: 4 coalesced float4 W1 loads +
// 13 broadcast ds_read_b128 of the context tile + 208 v_fma_f32.
__global__ __launch_bounds__(NT, 2)
void esa_fused(const int* __restrict__ x,
               const int* __restrict__ ctx,
               const float* __restrict__ embs,
               const float* __restrict__ W1,
               const float* __restrict__ b1,
               const float* __restrict__ W2,
               const float* __restrict__ b2,
               float* __restrict__ out)
{
    __shared__ float c_lds[52][NC];   // 52 rows: 50 real + 2 zero pad
    __shared__ float xemb[NC];
    __shared__ float pool4[4][NH];
    __shared__ float pooled[NH];

    const int b    = blockIdx.x;
    const int tid  = threadIdx.x;
    const int wave = tid >> 6;
    const int lane = tid & 63;

    // ---------------- phase 1: gather context rows + x row into LDS ----------
    for (int r = wave; r < CTXL; r += 4) {
        const int row = ctx[b * CTXL + r];
        const float4* src = (const float4*)(embs + (size_t)row * NC);
        float4* dst = (float4*)(&c_lds[r][0]);
        #pragma unroll
        for (int q = 0; q < 2; ++q) {
            const int idx = lane + 64 * q;
            if (idx < NC / 4) dst[idx] = src[idx];
        }
    }
    // zero the two pad rows (600 floats)
    for (int q = tid; q < 2 * NC; q += NT) (&c_lds[50][0])[q] = 0.0f;
    // x embedding row
    {
        const int row = x[b];
        const float4* src = (const float4*)(embs + (size_t)row * NC);
        float4* dst = (float4*)xemb;
        if (tid < NC / 4) dst[tid] = src[tid];
    }
    __syncthreads();

    // ---------------- phase 2: h = relu(c_embs @ W1 + b1), mean over l -------
    const int l0 = wave * 13;
    const int n0 = lane * 4;

    float4 acc[13];
    {
        const float4 bv = *(const float4*)(b1 + n0);
        #pragma unroll
        for (int l = 0; l < 13; ++l) acc[l] = bv;
    }

    for (int kb = 0; kb < NC; kb += 4) {
        const float4 wa = *(const float4*)(W1 + (size_t)(kb + 0) * NH + n0);
        const float4 wb = *(const float4*)(W1 + (size_t)(kb + 1) * NH + n0);
        const float4 wc = *(const float4*)(W1 + (size_t)(kb + 2) * NH + n0);
        const float4 wd = *(const float4*)(W1 + (size_t)(kb + 3) * NH + n0);
        #pragma unroll
        for (int l = 0; l < 13; ++l) {
            const float4 c4 = *(const float4*)(&c_lds[l0 + l][kb]);
            acc[l].x = fmaf(c4.x, wa.x, acc[l].x);
            acc[l].y = fmaf(c4.x, wa.y, acc[l].y);
            acc[l].z = fmaf(c4.x, wa.z, acc[l].z);
            acc[l].w = fmaf(c4.x, wa.w, acc[l].w);
            acc[l].x = fmaf(c4.y, wb.x, acc[l].x);
            acc[l].y = fmaf(c4.y, wb.y, acc[l].y);
            acc[l].z = fmaf(c4.y, wb.z, acc[l].z);
            acc[l].w = fmaf(c4.y, wb.w, acc[l].w);
            acc[l].x = fmaf(c4.z, wc.x, acc[l].x);
            acc[l].y = fmaf(c4.z, wc.y, acc[l].y);
            acc[l].z = fmaf(c4.z, wc.z, acc[l].z);
            acc[l].w = fmaf(c4.z, wc.w, acc[l].w);
            acc[l].x = fmaf(c4.w, wd.x, acc[l].x);
            acc[l].y = fmaf(c4.w, wd.y, acc[l].y);
            acc[l].z = fmaf(c4.w, wd.z, acc[l].z);
            acc[l].w = fmaf(c4.w, wd.w, acc[l].w);
        }
    }

    // relu + per-wave partial sum over this wave's l rows
    {
        float4 ps = make_float4(0.f, 0.f, 0.f, 0.f);
        #pragma unroll
        for (int l = 0; l < 13; ++l) {
            if (l0 + l < CTXL) {   // wave-uniform guard (wave 3 has 11 valid)
                ps.x += fmaxf(acc[l].x, 0.0f);
                ps.y += fmaxf(acc[l].y, 0.0f);
                ps.z += fmaxf(acc[l].z, 0.0f);
                ps.w += fmaxf(acc[l].w, 0.0f);
            }
        }
        *(float4*)(&pool4[wave][n0]) = ps;
    }
    __syncthreads();

    // cross-wave reduce + mean
    {
        const float p = (pool4[0][tid] + pool4[1][tid] +
                         pool4[2][tid] + pool4[3][tid]) * (1.0f / CTXL);
        pooled[tid] = p;
    }
    __syncthreads();

    // ---------------- phase 3: gate = sigmoid(pooled @ W2 + b2); out ---------
    for (int j = tid; j < NC; j += NT) {
        float s = b2[j];
        for (int k = 0; k < NH; k += 4) {
            const float4 p4 = *(const float4*)(&pooled[k]);
            s = fmaf(p4.x, W2[(size_t)(k + 0) * NC + j], s);
            s = fmaf(p4.y, W2[(size_t)(k + 1) * NC + j], s);
            s = fmaf(p4.z, W2[(size_t)(k + 2) * NC + j], s);
            s = fmaf(p4.w, W2[(size_t)(k + 3) * NC + j], s);
        }
        const float g = 1.0f / (1.0f + __expf(-s));
        out[(size_t)b * NC + j] = g * xemb[j];
    }
}

extern "C" void kernel_launch(void* const* d_in, const int* in_sizes, int n_in,
                              void* d_out, int out_size, void* d_ws, size_t ws_size,
                              hipStream_t stream) {
    const int*   x    = (const int*)d_in[0];
    const int*   ctx  = (const int*)d_in[1];
    const float* embs = (const float*)d_in[2];
    const float* W1   = (const float*)d_in[3];
    const float* b1   = (const float*)d_in[4];
    const float* W2   = (const float*)d_in[5];
    const float* b2   = (const float*)d_in[6];
    float* out = (float*)d_out;

    const int B = in_sizes[0];
    esa_fused<<<B, NT, 0, stream>>>(x, ctx, embs, W1, b1, W2, b2, out);
}

// Round 2
// 147.060 us; speedup vs baseline: 3.1332x; 3.1332x over previous
//
#include <hip/hip_runtime.h>
#include <cmath>

#define CTXL 50
#define NC 300    // NCOND
#define NH 256    // NHID
#define NT 256    // threads per block
#define KPAD 320  // K padded to 10 k-steps of 32
#define AROWS 52  // LDS A rows (50 real + 2 slack; m-tile 3 rows >=52 clamp to 0, masked)
#define ASTR 328  // A row stride in shorts (656 B = 164 dwords; 164%32=4 -> 2-way LDS aliasing, free)

typedef float  f32x4 __attribute__((ext_vector_type(4)));
typedef short  s16x8 __attribute__((ext_vector_type(8)));

__device__ __forceinline__ ushort f2bf(float f) {
    unsigned u = __float_as_uint(f);
    unsigned r = (u + 0x7FFFu + ((u >> 16) & 1u)) >> 16;   // RNE
    return (ushort)r;
}
__device__ __forceinline__ float bf2f(ushort u) {
    return __uint_as_float(((unsigned)u) << 16);
}

// ---------------------------------------------------------------------------
// pre-pass: W1 [300][256] f32 -> W1T bf16 [256][320] (transposed, K zero-pad)
//           W2 [256][300] f32 -> W2b bf16 flat
__global__ void convert_w(const float* __restrict__ W1, const float* __restrict__ W2,
                          ushort* __restrict__ W1T, ushort* __restrict__ W2b) {
    const int t = threadIdx.x;
    const int bidx = blockIdx.x;
    if (bidx < KPAD) {                 // blocks 0..319: k = bidx, thread = n
        const int k = bidx;
        W1T[(size_t)t * KPAD + k] = (k < NC) ? f2bf(W1[(size_t)k * NH + t]) : (ushort)0;
    } else {                           // blocks 320..619: flat W2 convert
        const int i = (bidx - KPAD) * NT + t;
        if (i < NH * NC) W2b[i] = f2bf(W2[i]);
    }
}

// ---------------------------------------------------------------------------
// main: one block per batch element. 4 waves; wave w owns cols [64w,64w+64).
__global__ __launch_bounds__(NT, 4)
void esa_mfma(const int* __restrict__ x,
              const int* __restrict__ ctx,
              const float* __restrict__ embs,
              const float* __restrict__ b1,
              const float* __restrict__ b2,
              const ushort* __restrict__ W1T,
              const ushort* __restrict__ W2b,
              float* __restrict__ out) {
    __shared__ short A[AROWS * ASTR];      // 34112 B, bf16 context tile (padded K)
    __shared__ float xemb[NC];             // 1200 B
    __shared__ float pooled[NH];           // 1024 B

    const int b    = blockIdx.x;
    const int tid  = threadIdx.x;
    const int wave = tid >> 6;
    const int lane = tid & 63;
    const int l15  = lane & 15;
    const int lhi  = lane >> 4;

    // -------- phase 1: gather 50 context rows -> bf16 LDS; x row -> LDS -----
    for (int r0 = 0; r0 < CTXL; r0 += 32) {
        const int r = r0 + (tid >> 3);
        if (r < CTXL) {
            const int row = ctx[b * CTXL + r];
            const float* src = embs + (size_t)row * NC;
            #pragma unroll
            for (int i = 0; i < 5; ++i) {
                const int c = (tid & 7) + 8 * i;      // 16B-chunk index 0..39
                const int k = c * 8;
                float v[8];
                if (c <= 36) {
                    const float4 a0 = *(const float4*)(src + k);
                    const float4 a1 = *(const float4*)(src + k + 4);
                    v[0]=a0.x; v[1]=a0.y; v[2]=a0.z; v[3]=a0.w;
                    v[4]=a1.x; v[5]=a1.y; v[6]=a1.z; v[7]=a1.w;
                } else if (c == 37) {                 // k 296..299 real, 300..303 zero
                    const float4 a0 = *(const float4*)(src + 296);
                    v[0]=a0.x; v[1]=a0.y; v[2]=a0.z; v[3]=a0.w;
                    v[4]=v[5]=v[6]=v[7]=0.0f;
                } else {                              // k 304..319 zero
                    #pragma unroll
                    for (int q = 0; q < 8; ++q) v[q] = 0.0f;
                }
                s16x8 p;
                #pragma unroll
                for (int q = 0; q < 8; ++q) p[q] = (short)f2bf(v[q]);
                *(s16x8*)((char*)A + (size_t)r * (ASTR * 2) + c * 16) = p;
            }
        }
    }
    {
        const int row = x[b];
        if (tid < NC / 4)
            ((float4*)xemb)[tid] = ((const float4*)(embs + (size_t)row * NC))[tid];
    }
    __syncthreads();

    // -------- phase 2: MFMA h = c_embs @ W1; relu+bias+mean fused ------------
    f32x4 acc[4][4];
    #pragma unroll
    for (int mt = 0; mt < 4; ++mt)
        #pragma unroll
        for (int nt = 0; nt < 4; ++nt)
            acc[mt][nt] = (f32x4){0.f, 0.f, 0.f, 0.f};

    int abyte[4];                                   // per-m-tile A row byte base
    #pragma unroll
    for (int mt = 0; mt < 4; ++mt) {
        int rr = mt * 16 + l15;
        if (rr >= AROWS) rr = 0;                    // clamped rows masked in pooling
        abyte[mt] = rr * (ASTR * 2) + lhi * 16;
    }
    const ushort* wbase = W1T + (size_t)(wave * 64 + l15) * KPAD + lhi * 8;

    #pragma unroll
    for (int ks = 0; ks < KPAD / 32; ++ks) {
        s16x8 af[4], bfr[4];
        #pragma unroll
        for (int mt = 0; mt < 4; ++mt)
            af[mt] = *(const s16x8*)((const char*)A + abyte[mt] + ks * 64);
        #pragma unroll
        for (int nt = 0; nt < 4; ++nt)
            bfr[nt] = *(const s16x8*)(wbase + nt * 16 * KPAD + ks * 32);
        #pragma unroll
        for (int mt = 0; mt < 4; ++mt)
            #pragma unroll
            for (int nt = 0; nt < 4; ++nt)
                acc[mt][nt] = __builtin_amdgcn_mfma_f32_16x16x32_bf16(
                    af[mt], bfr[nt], acc[mt][nt], 0, 0, 0);
    }

    // relu(acc + b1) masked mean over rows < 50; lane-local + cross-rowgroup shfl
    #pragma unroll
    for (int nt = 0; nt < 4; ++nt) {
        const float bb = b1[wave * 64 + nt * 16 + l15];
        float s = 0.0f;
        #pragma unroll
        for (int mt = 0; mt < 4; ++mt) {
            #pragma unroll
            for (int q = 0; q < 4; ++q) {
                const int row = mt * 16 + lhi * 4 + q;   // C/D: col=l15, row=4*lhi+q
                const float v = fmaxf(acc[mt][nt][q] + bb, 0.0f);
                s += (row < CTXL) ? v : 0.0f;
            }
        }
        s += __shfl_xor(s, 16);
        s += __shfl_xor(s, 32);
        if (lhi == 0) pooled[wave * 64 + nt * 16 + l15] = s * (1.0f / CTXL);
    }
    __syncthreads();

    // -------- phase 3: gate = sigmoid(pooled @ W2 + b2); out = gate*xemb ----
    for (int j = tid; j < NC; j += NT) {
        float s = b2[j];
        #pragma unroll 8
        for (int k = 0; k < NH; k += 4) {
            const float4 p = *(const float4*)(&pooled[k]);
            s = fmaf(p.x, bf2f(W2b[(size_t)(k + 0) * NC + j]), s);
            s = fmaf(p.y, bf2f(W2b[(size_t)(k + 1) * NC + j]), s);
            s = fmaf(p.z, bf2f(W2b[(size_t)(k + 2) * NC + j]), s);
            s = fmaf(p.w, bf2f(W2b[(size_t)(k + 3) * NC + j]), s);
        }
        const float g = 1.0f / (1.0f + __expf(-s));
        out[(size_t)b * NC + j] = g * xemb[j];
    }
}

// ---------------------------------------------------------------------------
// fallback (previous fp32 kernel) if ws is too small for weight staging
__global__ __launch_bounds__(NT, 2)
void esa_fused(const int* __restrict__ x, const int* __restrict__ ctx,
               const float* __restrict__ embs, const float* __restrict__ W1,
               const float* __restrict__ b1, const float* __restrict__ W2,
               const float* __restrict__ b2, float* __restrict__ out) {
    __shared__ float c_lds[52][NC];
    __shared__ float xemb[NC];
    __shared__ float pool4[4][NH];
    __shared__ float pooled[NH];
    const int b = blockIdx.x, tid = threadIdx.x, wave = tid >> 6, lane = tid & 63;
    for (int r = wave; r < CTXL; r += 4) {
        const int row = ctx[b * CTXL + r];
        const float4* src = (const float4*)(embs + (size_t)row * NC);
        float4* dst = (float4*)(&c_lds[r][0]);
        #pragma unroll
        for (int q = 0; q < 2; ++q) { const int idx = lane + 64 * q; if (idx < NC / 4) dst[idx] = src[idx]; }
    }
    for (int q = tid; q < 2 * NC; q += NT) (&c_lds[50][0])[q] = 0.0f;
    { const int row = x[b]; if (tid < NC / 4) ((float4*)xemb)[tid] = ((const float4*)(embs + (size_t)row * NC))[tid]; }
    __syncthreads();
    const int l0 = wave * 13, n0 = lane * 4;
    float4 acc[13];
    { const float4 bv = *(const float4*)(b1 + n0);
      #pragma unroll
      for (int l = 0; l < 13; ++l) acc[l] = bv; }
    for (int kb = 0; kb < NC; kb += 4) {
        const float4 wa = *(const float4*)(W1 + (size_t)(kb + 0) * NH + n0);
        const float4 wb = *(const float4*)(W1 + (size_t)(kb + 1) * NH + n0);
        const float4 wc = *(const float4*)(W1 + (size_t)(kb + 2) * NH + n0);
        const float4 wd = *(const float4*)(W1 + (size_t)(kb + 3) * NH + n0);
        #pragma unroll
        for (int l = 0; l < 13; ++l) {
            const float4 c4 = *(const float4*)(&c_lds[l0 + l][kb]);
            acc[l].x = fmaf(c4.x, wa.x, acc[l].x); acc[l].y = fmaf(c4.x, wa.y, acc[l].y);
            acc[l].z = fmaf(c4.x, wa.z, acc[l].z); acc[l].w = fmaf(c4.x, wa.w, acc[l].w);
            acc[l].x = fmaf(c4.y, wb.x, acc[l].x); acc[l].y = fmaf(c4.y, wb.y, acc[l].y);
            acc[l].z = fmaf(c4.y, wb.z, acc[l].z); acc[l].w = fmaf(c4.y, wb.w, acc[l].w);
            acc[l].x = fmaf(c4.z, wc.x, acc[l].x); acc[l].y = fmaf(c4.z, wc.y, acc[l].y);
            acc[l].z = fmaf(c4.z, wc.z, acc[l].z); acc[l].w = fmaf(c4.z, wc.w, acc[l].w);
            acc[l].x = fmaf(c4.w, wd.x, acc[l].x); acc[l].y = fmaf(c4.w, wd.y, acc[l].y);
            acc[l].z = fmaf(c4.w, wd.z, acc[l].z); acc[l].w = fmaf(c4.w, wd.w, acc[l].w);
        }
    }
    { float4 ps = make_float4(0.f, 0.f, 0.f, 0.f);
      #pragma unroll
      for (int l = 0; l < 13; ++l) if (l0 + l < CTXL) {
          ps.x += fmaxf(acc[l].x, 0.f); ps.y += fmaxf(acc[l].y, 0.f);
          ps.z += fmaxf(acc[l].z, 0.f); ps.w += fmaxf(acc[l].w, 0.f); }
      *(float4*)(&pool4[wave][n0]) = ps; }
    __syncthreads();
    pooled[tid] = (pool4[0][tid] + pool4[1][tid] + pool4[2][tid] + pool4[3][tid]) * (1.0f / CTXL);
    __syncthreads();
    for (int j = tid; j < NC; j += NT) {
        float s = b2[j];
        for (int k = 0; k < NH; k += 4) {
            const float4 p4 = *(const float4*)(&pooled[k]);
            s = fmaf(p4.x, W2[(size_t)(k + 0) * NC + j], s);
            s = fmaf(p4.y, W2[(size_t)(k + 1) * NC + j], s);
            s = fmaf(p4.z, W2[(size_t)(k + 2) * NC + j], s);
            s = fmaf(p4.w, W2[(size_t)(k + 3) * NC + j], s);
        }
        const float g = 1.0f / (1.0f + __expf(-s));
        out[(size_t)b * NC + j] = g * xemb[j];
    }
}

extern "C" void kernel_launch(void* const* d_in, const int* in_sizes, int n_in,
                              void* d_out, int out_size, void* d_ws, size_t ws_size,
                              hipStream_t stream) {
    const int*   x    = (const int*)d_in[0];
    const int*   ctx  = (const int*)d_in[1];
    const float* embs = (const float*)d_in[2];
    const float* W1   = (const float*)d_in[3];
    const float* b1   = (const float*)d_in[4];
    const float* W2   = (const float*)d_in[5];
    const float* b2   = (const float*)d_in[6];
    float* out = (float*)d_out;
    const int B = in_sizes[0];

    const size_t w1t_bytes = (size_t)NH * KPAD * 2;   // 163840
    const size_t w2b_bytes = (size_t)NH * NC * 2;     // 153600

    if (ws_size >= w1t_bytes + w2b_bytes) {
        ushort* W1T = (ushort*)d_ws;
        ushort* W2b = (ushort*)((char*)d_ws + w1t_bytes);
        convert_w<<<KPAD + (NH * NC + NT - 1) / NT, NT, 0, stream>>>(W1, W2, W1T, W2b);
        esa_mfma<<<B, NT, 0, stream>>>(x, ctx, embs, b1, b2, W1T, W2b, out);
    } else {
        esa_fused<<<B, NT, 0, stream>>>(x, ctx, embs, W1, b1, W2, b2, out);
    }
}